// Round 1
// baseline (666.633 us; speedup 1.0000x reference)
//
#include <hip/hip_runtime.h>
#include <hip/hip_bf16.h>

// Problem constants (from reference)
#define N0 409600
#define N1 40960
#define N2 4096
#define E1 409600
#define E2 40960
#define F_IN 512
#define F_HID 256
#define F_OUT 128

// ---------------- histogram ----------------
__global__ void k_hist(const int* __restrict__ dst, int* __restrict__ cnt, int E) {
    int e = blockIdx.x * blockDim.x + threadIdx.x;
    if (e < E) atomicAdd(&cnt[dst[e]], 1);
}

// ---------------- single-block exclusive scan (n multiple of 1024 ok, handles any n) ----------------
__global__ void k_scan(const int* __restrict__ cnt, int* __restrict__ off,
                       int* __restrict__ cursor, int n) {
    __shared__ int buf[1024];
    __shared__ int carry;
    int t = threadIdx.x;
    if (t == 0) carry = 0;
    __syncthreads();
    for (int base = 0; base < n; base += 1024) {
        int i = base + t;
        int v = (i < n) ? cnt[i] : 0;
        buf[t] = v;
        __syncthreads();
        for (int s = 1; s < 1024; s <<= 1) {
            int add = (t >= s) ? buf[t - s] : 0;
            __syncthreads();
            buf[t] += add;
            __syncthreads();
        }
        int excl = buf[t] - v;
        int c = carry;
        if (i < n) { off[i] = c + excl; cursor[i] = c + excl; }
        __syncthreads();
        if (t == 1023) carry = c + buf[1023];
        __syncthreads();
    }
    if (t == 0) off[n] = carry;
}

// ---------------- scatter edge ids into CSR buckets ----------------
__global__ void k_scatter(const int* __restrict__ src, const int* __restrict__ dst,
                          int* __restrict__ cursor, int* __restrict__ perm, int E) {
    int e = blockIdx.x * blockDim.x + threadIdx.x;
    if (e < E) {
        int d = dst[e];
        int pos = atomicAdd(&cursor[d], 1);
        perm[pos] = src[e];
    }
}

// ---------------- per-dst mean aggregation (block per dst, float2 per thread) ----------------
// blockDim.x must be F/2
__global__ void k_agg(const float* __restrict__ x, const int* __restrict__ perm,
                      const int* __restrict__ off, float* __restrict__ mean) {
    int d = blockIdx.x;
    int beg = off[d], end = off[d + 1];
    int t = threadIdx.x;
    int Fh = blockDim.x;
    const float2* xp = (const float2*)x;
    float ax = 0.f, ay = 0.f;
    int e = beg;
    for (; e + 1 < end; e += 2) {
        int s0 = perm[e];
        int s1 = perm[e + 1];
        float2 v0 = xp[(size_t)s0 * Fh + t];
        float2 v1 = xp[(size_t)s1 * Fh + t];
        ax += v0.x + v1.x;
        ay += v0.y + v1.y;
    }
    if (e < end) {
        int s0 = perm[e];
        float2 v0 = xp[(size_t)s0 * Fh + t];
        ax += v0.x;
        ay += v0.y;
    }
    int deg = end - beg;
    float inv = 1.0f / (float)(deg > 0 ? deg : 1);
    float2 o;
    o.x = ax * inv;
    o.y = ay * inv;
    ((float2*)mean)[(size_t)d * Fh + t] = o;
}

// ---------------- dual-A GEMM: C = A1@B1 + A2@B2 + bias, optional relu ----------------
// A1, A2: M x K row-major. B1, B2: K x N row-major. C: M x N.
// BM=64, BN=64, BK=16, 256 threads, 4x4 per thread.
#define BM 64
#define BN 64
#define BK 16
__global__ __launch_bounds__(256) void k_gemm_dual(
    const float* __restrict__ A1, const float* __restrict__ A2,
    const float* __restrict__ B1, const float* __restrict__ B2,
    const float* __restrict__ bias, float* __restrict__ C,
    int M, int N, int K, int relu) {
    __shared__ float As[BK][BM + 1];
    __shared__ float Bs[BK][BN];
    int tid = threadIdx.x;
    int bm = blockIdx.x, bn = blockIdx.y;
    int ty = tid >> 4, tx = tid & 15;
    float acc[4][4] = {};
    for (int part = 0; part < 2; ++part) {
        const float* __restrict__ A = part ? A2 : A1;
        const float* __restrict__ B = part ? B2 : B1;
        for (int k0 = 0; k0 < K; k0 += BK) {
#pragma unroll
            for (int i = 0; i < 4; i++) {
                int idx = tid + i * 256;
                int r = idx >> 4, c = idx & 15;
                As[c][r] = A[(size_t)(bm * BM + r) * K + k0 + c];
            }
#pragma unroll
            for (int i = 0; i < 4; i++) {
                int idx = tid + i * 256;
                int kk = idx >> 6, n = idx & 63;
                Bs[kk][n] = B[(size_t)(k0 + kk) * N + bn * BN + n];
            }
            __syncthreads();
#pragma unroll
            for (int kk = 0; kk < BK; kk++) {
                float a[4], b[4];
#pragma unroll
                for (int i = 0; i < 4; i++) a[i] = As[kk][ty * 4 + i];
#pragma unroll
                for (int j = 0; j < 4; j++) b[j] = Bs[kk][tx * 4 + j];
#pragma unroll
                for (int i = 0; i < 4; i++)
#pragma unroll
                    for (int j = 0; j < 4; j++) acc[i][j] += a[i] * b[j];
            }
            __syncthreads();
        }
    }
#pragma unroll
    for (int i = 0; i < 4; i++) {
        int row = bm * BM + ty * 4 + i;
#pragma unroll
        for (int j = 0; j < 4; j++) {
            int col = bn * BN + tx * 4 + j;
            float v = acc[i][j] + bias[col];
            if (relu) v = fmaxf(v, 0.f);
            C[(size_t)row * N + col] = v;
        }
    }
}

static inline size_t align256(size_t x) { return (x + 255) & ~(size_t)255; }

extern "C" void kernel_launch(void* const* d_in, const int* in_sizes, int n_in,
                              void* d_out, int out_size, void* d_ws, size_t ws_size,
                              hipStream_t stream) {
    const float* x = (const float*)d_in[0];
    const int* ei1_src = (const int*)d_in[1];
    const int* ei1_dst = (const int*)d_in[2];
    const int* ei2_src = (const int*)d_in[3];
    const int* ei2_dst = (const int*)d_in[4];
    const float* W1l = (const float*)d_in[5];
    const float* b1 = (const float*)d_in[6];
    const float* W1r = (const float*)d_in[7];
    const float* W2l = (const float*)d_in[8];
    const float* b2 = (const float*)d_in[9];
    const float* W2r = (const float*)d_in[10];
    float* out = (float*)d_out;

    // workspace layout
    char* p = (char*)d_ws;
    size_t o = 0;
    int* cnt1 = (int*)(p + o); o = align256(o + (size_t)N1 * 4);
    int* off1 = (int*)(p + o); o = align256(o + (size_t)(N1 + 1) * 4);
    int* cur1 = (int*)(p + o); o = align256(o + (size_t)N1 * 4);
    int* perm1 = (int*)(p + o); o = align256(o + (size_t)E1 * 4);
    int* cnt2 = (int*)(p + o); o = align256(o + (size_t)N2 * 4);
    int* off2 = (int*)(p + o); o = align256(o + (size_t)(N2 + 1) * 4);
    int* cur2 = (int*)(p + o); o = align256(o + (size_t)N2 * 4);
    int* perm2 = (int*)(p + o); o = align256(o + (size_t)E2 * 4);
    float* mean1 = (float*)(p + o); o = align256(o + (size_t)N1 * F_IN * 4);
    float* h = (float*)(p + o); o = align256(o + (size_t)N1 * F_HID * 4);
    float* mean2 = (float*)(p + o); o = align256(o + (size_t)N2 * F_HID * 4);

    // zero histograms
    hipMemsetAsync(cnt1, 0, (size_t)N1 * 4, stream);
    hipMemsetAsync(cnt2, 0, (size_t)N2 * 4, stream);

    // layer-1 CSR build
    k_hist<<<(E1 + 255) / 256, 256, 0, stream>>>(ei1_dst, cnt1, E1);
    k_scan<<<1, 1024, 0, stream>>>(cnt1, off1, cur1, N1);
    k_scatter<<<(E1 + 255) / 256, 256, 0, stream>>>(ei1_src, ei1_dst, cur1, perm1, E1);
    // layer-2 CSR build (independent of layer-1 compute)
    k_hist<<<(E2 + 255) / 256, 256, 0, stream>>>(ei2_dst, cnt2, E2);
    k_scan<<<1, 1024, 0, stream>>>(cnt2, off2, cur2, N2);
    k_scatter<<<(E2 + 255) / 256, 256, 0, stream>>>(ei2_src, ei2_dst, cur2, perm2, E2);

    // layer-1 aggregate (mean over neighbors, F_IN features)
    k_agg<<<N1, F_IN / 2, 0, stream>>>(x, perm1, off1, mean1);
    // h = relu(mean1@W1l + b1 + x[:N1]@W1r)
    {
        dim3 grid(N1 / BM, F_HID / BN);
        k_gemm_dual<<<grid, 256, 0, stream>>>(mean1, x, W1l, W1r, b1, h,
                                              N1, F_HID, F_IN, 1);
    }
    // layer-2 aggregate over h
    k_agg<<<N2, F_HID / 2, 0, stream>>>(h, perm2, off2, mean2);
    // out = mean2@W2l + b2 + h[:N2]@W2r
    {
        dim3 grid(N2 / BM, F_OUT / BN);
        k_gemm_dual<<<grid, 256, 0, stream>>>(mean2, h, W2l, W2r, b2, out,
                                              N2, F_OUT, F_HID, 0);
    }
}

// Round 3
// 354.184 us; speedup vs baseline: 1.8822x; 1.8822x over previous
//
#include <hip/hip_runtime.h>
#include <hip/hip_bf16.h>

// Problem constants (from reference)
#define N0 409600
#define N1 40960
#define N2 4096
#define E1c 409600
#define E2c 40960
#define F_IN 512
#define F_HID 256
#define F_OUT 128

using bf16x8 = __attribute__((ext_vector_type(8))) short;
using f32x4  = __attribute__((ext_vector_type(4))) float;

__device__ __forceinline__ ushort f2bf(float f) {
    union { float f; unsigned u; } v; v.f = f;
    unsigned r = v.u + 0x7fffu + ((v.u >> 16) & 1u);
    return (ushort)(r >> 16);
}
__device__ __forceinline__ float bf2f(ushort b) {
    union { unsigned u; float f; } v; v.u = ((unsigned)b) << 16;
    return v.f;
}

// ---------------- histogram ----------------
__global__ void k_hist(const int* __restrict__ dst, int* __restrict__ cnt, int E) {
    int e = blockIdx.x * blockDim.x + threadIdx.x;
    if (e < E) atomicAdd(&cnt[dst[e]], 1);
}

// ---------------- single-block exclusive scan, wave-shuffle based ----------------
__global__ void k_scan(const int* __restrict__ cnt, int* __restrict__ off,
                       int* __restrict__ cursor, int n) {
    __shared__ int wsum[16];
    int t = threadIdx.x, lane = t & 63, w = t >> 6;
    int carry = 0;
    for (int base = 0; base < n; base += 1024) {
        int i = base + t;
        int v = (i < n) ? cnt[i] : 0;
        int s = v;
#pragma unroll
        for (int d = 1; d < 64; d <<= 1) {
            int u = __shfl_up(s, d, 64);
            if (lane >= d) s += u;
        }
        if (lane == 63) wsum[w] = s;
        __syncthreads();
        int wpre = 0, total = 0;
#pragma unroll
        for (int j = 0; j < 16; j++) {
            int u = wsum[j];
            if (j < w) wpre += u;
            total += u;
        }
        int excl = carry + wpre + (s - v);
        if (i < n) { off[i] = excl; cursor[i] = excl; }
        carry += total;
        __syncthreads();
    }
    if (t == 0) off[n] = carry;
}

// ---------------- scatter edge ids into CSR buckets ----------------
__global__ void k_scatter(const int* __restrict__ src, const int* __restrict__ dst,
                          int* __restrict__ cursor, int* __restrict__ perm, int E) {
    int e = blockIdx.x * blockDim.x + threadIdx.x;
    if (e < E) {
        int d = dst[e];
        int pos = atomicAdd(&cursor[d], 1);
        perm[pos] = src[e];
    }
}

// ---------------- f32 -> bf16 bulk convert (float4 granularity) ----------------
__global__ void k_cvt_bf16(const float* __restrict__ in, ushort* __restrict__ out, int n4) {
    int i = blockIdx.x * blockDim.x + threadIdx.x;
    if (i >= n4) return;
    float4 v = ((const float4*)in)[i];
    ushort4 o;
    o.x = f2bf(v.x); o.y = f2bf(v.y); o.z = f2bf(v.z); o.w = f2bf(v.w);
    ((ushort4*)out)[i] = o;
}

// ---------------- W (KxN f32, row-major) -> WT (NxK bf16) ----------------
__global__ void k_wt(const float* __restrict__ W, ushort* __restrict__ WT, int K, int N) {
    int idx = blockIdx.x * blockDim.x + threadIdx.x;
    if (idx >= K * N) return;
    int k = idx / N, n = idx % N;
    WT[(size_t)n * K + k] = f2bf(W[idx]);
}

// ---------------- layer-1 aggregation: f32 gather -> bf16 mean. block=128 (F_IN/4) ----
__global__ void k_agg1(const float* __restrict__ x, const int* __restrict__ perm,
                       const int* __restrict__ off, ushort* __restrict__ mean) {
    int d = blockIdx.x;
    int beg = off[d], end = off[d + 1];
    int t = threadIdx.x;
    const float4* xp = (const float4*)x;
    float ax = 0.f, ay = 0.f, az = 0.f, aw = 0.f;
    int e = beg;
    for (; e + 1 < end; e += 2) {
        int s0 = perm[e], s1 = perm[e + 1];
        float4 v0 = xp[(size_t)s0 * (F_IN / 4) + t];
        float4 v1 = xp[(size_t)s1 * (F_IN / 4) + t];
        ax += v0.x + v1.x; ay += v0.y + v1.y;
        az += v0.z + v1.z; aw += v0.w + v1.w;
    }
    if (e < end) {
        float4 v0 = xp[(size_t)perm[e] * (F_IN / 4) + t];
        ax += v0.x; ay += v0.y; az += v0.z; aw += v0.w;
    }
    int deg = end - beg;
    float inv = 1.0f / (float)(deg > 0 ? deg : 1);
    ushort4 o;
    o.x = f2bf(ax * inv); o.y = f2bf(ay * inv);
    o.z = f2bf(az * inv); o.w = f2bf(aw * inv);
    ((ushort4*)mean)[(size_t)d * (F_IN / 4) + t] = o;
}

// ---------------- layer-2 aggregation: bf16 gather -> bf16 mean. block=64 (F_HID/4) ----
__global__ void k_agg2(const ushort* __restrict__ h, const int* __restrict__ perm,
                       const int* __restrict__ off, ushort* __restrict__ mean) {
    int d = blockIdx.x;
    int beg = off[d], end = off[d + 1];
    int t = threadIdx.x;
    const ushort4* hp = (const ushort4*)h;
    float a0 = 0.f, a1 = 0.f, a2 = 0.f, a3 = 0.f;
    int e = beg;
    for (; e + 1 < end; e += 2) {
        ushort4 v = hp[(size_t)perm[e] * (F_HID / 4) + t];
        ushort4 u = hp[(size_t)perm[e + 1] * (F_HID / 4) + t];
        a0 += bf2f(v.x) + bf2f(u.x); a1 += bf2f(v.y) + bf2f(u.y);
        a2 += bf2f(v.z) + bf2f(u.z); a3 += bf2f(v.w) + bf2f(u.w);
    }
    if (e < end) {
        ushort4 v = hp[(size_t)perm[e] * (F_HID / 4) + t];
        a0 += bf2f(v.x); a1 += bf2f(v.y); a2 += bf2f(v.z); a3 += bf2f(v.w);
    }
    int deg = end - beg;
    float inv = 1.0f / (float)(deg > 0 ? deg : 1);
    ushort4 o;
    o.x = f2bf(a0 * inv); o.y = f2bf(a1 * inv);
    o.z = f2bf(a2 * inv); o.w = f2bf(a3 * inv);
    ((ushort4*)mean)[(size_t)d * (F_HID / 4) + t] = o;
}

// ---------------- dual-A bf16 MFMA GEMM ----------------
// C = A1@B1^T + A2@B2^T + bias  (B given pre-transposed NxK)
// A1,A2: MxK bf16 row-major. B1T,B2T: NxK bf16 row-major. 128x128 tile, 4 waves.
#define GBM 128
#define GBN 128
#define GBK 32
#define APAD 8
__global__ __launch_bounds__(256) void k_gemm_mfma(
    const ushort* __restrict__ A1, const ushort* __restrict__ A2,
    const ushort* __restrict__ B1T, const ushort* __restrict__ B2T,
    const float* __restrict__ bias, int M, int N, int K, int relu,
    ushort* __restrict__ Cb, float* __restrict__ Cf)
{
    __shared__ ushort As[GBM][GBK + APAD];
    __shared__ ushort Bs[GBN][GBK + APAD];
    int tid = threadIdx.x;
    int lane = tid & 63;
    int wid = tid >> 6;
    int wm = wid >> 1, wn = wid & 1;   // 2x2 waves, each computes 64x64
    int bm = blockIdx.x * GBM, bn = blockIdx.y * GBN;

    f32x4 acc[4][4];
#pragma unroll
    for (int i = 0; i < 4; i++)
#pragma unroll
        for (int j = 0; j < 4; j++) acc[i][j] = (f32x4){0.f, 0.f, 0.f, 0.f};

    int sr = tid >> 2;        // 0..63
    int sc = (tid & 3) * 8;   // 0,8,16,24

    for (int part = 0; part < 2; ++part) {
        const ushort* __restrict__ A = part ? A2 : A1;
        const ushort* __restrict__ B = part ? B2T : B1T;
        for (int k0 = 0; k0 < K; k0 += GBK) {
#pragma unroll
            for (int i = 0; i < 2; i++) {
                int r = sr + i * 64;
                *(bf16x8*)&As[r][sc] = *(const bf16x8*)&A[(size_t)(bm + r) * K + k0 + sc];
                *(bf16x8*)&Bs[r][sc] = *(const bf16x8*)&B[(size_t)(bn + r) * K + k0 + sc];
            }
            __syncthreads();
            bf16x8 af[4], bfr[4];
            int r0 = lane & 15;
            int kq = (lane >> 4) * 8;
#pragma unroll
            for (int i = 0; i < 4; i++)
                af[i] = *(const bf16x8*)&As[wm * 64 + i * 16 + r0][kq];
#pragma unroll
            for (int j = 0; j < 4; j++)
                bfr[j] = *(const bf16x8*)&Bs[wn * 64 + j * 16 + r0][kq];
#pragma unroll
            for (int i = 0; i < 4; i++)
#pragma unroll
                for (int j = 0; j < 4; j++)
                    acc[i][j] = __builtin_amdgcn_mfma_f32_16x16x32_bf16(af[i], bfr[j], acc[i][j], 0, 0, 0);
            __syncthreads();
        }
    }

    // C/D layout: col = lane&15, row = (lane>>4)*4 + reg
    int cn0 = lane & 15;
    int rq = (lane >> 4) * 4;
#pragma unroll
    for (int i = 0; i < 4; i++) {
#pragma unroll
        for (int j = 0; j < 4; j++) {
            int col = bn + wn * 64 + j * 16 + cn0;
            float bv = bias[col];
#pragma unroll
            for (int rr = 0; rr < 4; rr++) {
                int row = bm + wm * 64 + i * 16 + rq + rr;
                float v = acc[i][j][rr] + bv;
                if (relu) v = fmaxf(v, 0.f);
                if (Cb) Cb[(size_t)row * N + col] = f2bf(v);
                if (Cf) Cf[(size_t)row * N + col] = v;
            }
        }
    }
}

static inline size_t align256(size_t x) { return (x + 255) & ~(size_t)255; }

extern "C" void kernel_launch(void* const* d_in, const int* in_sizes, int n_in,
                              void* d_out, int out_size, void* d_ws, size_t ws_size,
                              hipStream_t stream) {
    const float* x = (const float*)d_in[0];
    const int* ei1_src = (const int*)d_in[1];
    const int* ei1_dst = (const int*)d_in[2];
    const int* ei2_src = (const int*)d_in[3];
    const int* ei2_dst = (const int*)d_in[4];
    const float* W1l = (const float*)d_in[5];
    const float* b1 = (const float*)d_in[6];
    const float* W1r = (const float*)d_in[7];
    const float* W2l = (const float*)d_in[8];
    const float* b2 = (const float*)d_in[9];
    const float* W2r = (const float*)d_in[10];
    float* out = (float*)d_out;

    // workspace layout
    char* p = (char*)d_ws;
    size_t o = 0;
    int* cnt1 = (int*)(p + o); o = align256(o + (size_t)N1 * 4);
    int* off1 = (int*)(p + o); o = align256(o + (size_t)(N1 + 1) * 4);
    int* cur1 = (int*)(p + o); o = align256(o + (size_t)N1 * 4);
    int* perm1 = (int*)(p + o); o = align256(o + (size_t)E1c * 4);
    int* cnt2 = (int*)(p + o); o = align256(o + (size_t)N2 * 4);
    int* off2 = (int*)(p + o); o = align256(o + (size_t)(N2 + 1) * 4);
    int* cur2 = (int*)(p + o); o = align256(o + (size_t)N2 * 4);
    int* perm2 = (int*)(p + o); o = align256(o + (size_t)E2c * 4);
    ushort* x1b   = (ushort*)(p + o); o = align256(o + (size_t)N1 * F_IN * 2);
    ushort* mean1 = (ushort*)(p + o); o = align256(o + (size_t)N1 * F_IN * 2);
    ushort* h     = (ushort*)(p + o); o = align256(o + (size_t)N1 * F_HID * 2);
    ushort* mean2 = (ushort*)(p + o); o = align256(o + (size_t)N2 * F_HID * 2);
    ushort* W1lT  = (ushort*)(p + o); o = align256(o + (size_t)F_IN * F_HID * 2);
    ushort* W1rT  = (ushort*)(p + o); o = align256(o + (size_t)F_IN * F_HID * 2);
    ushort* W2lT  = (ushort*)(p + o); o = align256(o + (size_t)F_HID * F_OUT * 2);
    ushort* W2rT  = (ushort*)(p + o); o = align256(o + (size_t)F_HID * F_OUT * 2);

    // zero histograms
    hipMemsetAsync(cnt1, 0, (size_t)N1 * 4, stream);
    hipMemsetAsync(cnt2, 0, (size_t)N2 * 4, stream);

    // CSR builds
    k_hist<<<(E1c + 255) / 256, 256, 0, stream>>>(ei1_dst, cnt1, E1c);
    k_hist<<<(E2c + 255) / 256, 256, 0, stream>>>(ei2_dst, cnt2, E2c);
    k_scan<<<1, 1024, 0, stream>>>(cnt1, off1, cur1, N1);
    k_scan<<<1, 1024, 0, stream>>>(cnt2, off2, cur2, N2);
    k_scatter<<<(E1c + 255) / 256, 256, 0, stream>>>(ei1_src, ei1_dst, cur1, perm1, E1c);
    k_scatter<<<(E2c + 255) / 256, 256, 0, stream>>>(ei2_src, ei2_dst, cur2, perm2, E2c);

    // weight transpose + convert, x[:N1] convert
    k_wt<<<(F_IN * F_HID + 255) / 256, 256, 0, stream>>>(W1l, W1lT, F_IN, F_HID);
    k_wt<<<(F_IN * F_HID + 255) / 256, 256, 0, stream>>>(W1r, W1rT, F_IN, F_HID);
    k_wt<<<(F_HID * F_OUT + 255) / 256, 256, 0, stream>>>(W2l, W2lT, F_HID, F_OUT);
    k_wt<<<(F_HID * F_OUT + 255) / 256, 256, 0, stream>>>(W2r, W2rT, F_HID, F_OUT);
    {
        int n4 = N1 * F_IN / 4;
        k_cvt_bf16<<<(n4 + 255) / 256, 256, 0, stream>>>(x, x1b, n4);
    }

    // layer 1: aggregate + GEMM
    k_agg1<<<N1, F_IN / 4, 0, stream>>>(x, perm1, off1, mean1);
    {
        dim3 grid(N1 / GBM, F_HID / GBN);
        k_gemm_mfma<<<grid, 256, 0, stream>>>(mean1, x1b, W1lT, W1rT, b1,
                                              N1, F_HID, F_IN, 1, h, nullptr);
    }

    // layer 2: aggregate + GEMM
    k_agg2<<<N2, F_HID / 4, 0, stream>>>(h, perm2, off2, mean2);
    {
        dim3 grid(N2 / GBM, F_OUT / GBN);
        k_gemm_mfma<<<grid, 256, 0, stream>>>(mean2, h, W2lT, W2rT, b2,
                                              N2, F_OUT, F_HID, 0, nullptr, out);
    }
}

// Round 4
// 279.422 us; speedup vs baseline: 2.3858x; 1.2676x over previous
//
#include <hip/hip_runtime.h>
#include <hip/hip_bf16.h>

// Problem constants (from reference)
#define N0 409600
#define N1 40960
#define N2 4096
#define E1c 409600
#define E2c 40960
#define F_IN 512
#define F_HID 256
#define F_OUT 128

using bf16x8 = __attribute__((ext_vector_type(8))) short;
using f32x4  = __attribute__((ext_vector_type(4))) float;

__device__ __forceinline__ ushort f2bf(float f) {
    union { float f; unsigned u; } v; v.f = f;
    unsigned r = v.u + 0x7fffu + ((v.u >> 16) & 1u);
    return (ushort)(r >> 16);
}
__device__ __forceinline__ float bf2f(ushort b) {
    union { unsigned u; float f; } v; v.u = ((unsigned)b) << 16;
    return v.f;
}

// load 8 contiguous elements as bf16x8 (identity for bf16, convert for f32)
__device__ __forceinline__ bf16x8 load8(const ushort* p) {
    return *(const bf16x8*)p;
}
__device__ __forceinline__ bf16x8 load8(const float* p) {
    float4 a = *(const float4*)p;
    float4 b = *(const float4*)(p + 4);
    bf16x8 r;
    r[0] = (short)f2bf(a.x); r[1] = (short)f2bf(a.y);
    r[2] = (short)f2bf(a.z); r[3] = (short)f2bf(a.w);
    r[4] = (short)f2bf(b.x); r[5] = (short)f2bf(b.y);
    r[6] = (short)f2bf(b.z); r[7] = (short)f2bf(b.w);
    return r;
}

// ---------------- fused histogram (both layers) ----------------
__global__ void k_hist2(const int* __restrict__ dst1, int* __restrict__ cnt1,
                        const int* __restrict__ dst2, int* __restrict__ cnt2) {
    int e = blockIdx.x * blockDim.x + threadIdx.x;
    if (e < E1c) atomicAdd(&cnt1[dst1[e]], 1);
    else {
        int e2 = e - E1c;
        if (e2 < E2c) atomicAdd(&cnt2[dst2[e2]], 1);
    }
}

// ---------------- hierarchical scan, phase A: per-1024 block scan ----------------
__global__ __launch_bounds__(1024) void k_scanA(const int* __restrict__ cnt,
                                                int* __restrict__ off,
                                                int* __restrict__ bsum, int n) {
    __shared__ int wsum[16];
    int t = threadIdx.x, lane = t & 63, w = t >> 6;
    int i = blockIdx.x * 1024 + t;
    int v = (i < n) ? cnt[i] : 0;
    int s = v;
#pragma unroll
    for (int d = 1; d < 64; d <<= 1) {
        int u = __shfl_up(s, d, 64);
        if (lane >= d) s += u;
    }
    if (lane == 63) wsum[w] = s;
    __syncthreads();
    int wpre = 0, total = 0;
#pragma unroll
    for (int j = 0; j < 16; j++) {
        int u = wsum[j];
        if (j < w) wpre += u;
        total += u;
    }
    if (i < n) off[i] = wpre + (s - v);
    if (t == 0) bsum[blockIdx.x] = total;
}

// ---------------- phase B: add block prefix, write cursor, write off[n] ----------------
__global__ __launch_bounds__(1024) void k_scanB(int* __restrict__ off,
                                                int* __restrict__ cursor,
                                                const int* __restrict__ bsum,
                                                int n, int nblk) {
    __shared__ int pre_s;
    int blk = blockIdx.x, t = threadIdx.x;
    if (t == 0) {
        int p = 0;
        for (int j = 0; j < blk; j++) p += bsum[j];
        pre_s = p;
        if (blk == nblk - 1) off[n] = p + bsum[blk];
    }
    __syncthreads();
    int i = blk * 1024 + t;
    if (i < n) {
        int val = off[i] + pre_s;
        off[i] = val;
        cursor[i] = val;
    }
}

// ---------------- fused scatter (both layers) ----------------
__global__ void k_scatter2(const int* __restrict__ src1, const int* __restrict__ dst1,
                           int* __restrict__ cur1, int* __restrict__ perm1,
                           const int* __restrict__ src2, const int* __restrict__ dst2,
                           int* __restrict__ cur2, int* __restrict__ perm2) {
    int e = blockIdx.x * blockDim.x + threadIdx.x;
    if (e < E1c) {
        int d = dst1[e];
        int pos = atomicAdd(&cur1[d], 1);
        perm1[pos] = src1[e];
    } else {
        int e2 = e - E1c;
        if (e2 < E2c) {
            int d = dst2[e2];
            int pos = atomicAdd(&cur2[d], 1);
            perm2[pos] = src2[e2];
        }
    }
}

// ---------------- fused weight transpose+convert (all 4 weights) ----------------
__global__ void k_wt_all(const float* __restrict__ W1l, const float* __restrict__ W1r,
                         const float* __restrict__ W2l, const float* __restrict__ W2r,
                         ushort* __restrict__ W1lT, ushort* __restrict__ W1rT,
                         ushort* __restrict__ W2lT, ushort* __restrict__ W2rT) {
    int idx = blockIdx.x * blockDim.x + threadIdx.x;
    const int S1 = F_IN * F_HID;   // 131072
    const int S2 = F_HID * F_OUT;  // 32768
    if (idx < S1) {
        int k = idx / F_HID, n = idx % F_HID;
        W1lT[(size_t)n * F_IN + k] = f2bf(W1l[idx]);
    } else if (idx < 2 * S1) {
        int j = idx - S1;
        int k = j / F_HID, n = j % F_HID;
        W1rT[(size_t)n * F_IN + k] = f2bf(W1r[j]);
    } else if (idx < 2 * S1 + S2) {
        int j = idx - 2 * S1;
        int k = j / F_OUT, n = j % F_OUT;
        W2lT[(size_t)n * F_HID + k] = f2bf(W2l[j]);
    } else if (idx < 2 * S1 + 2 * S2) {
        int j = idx - 2 * S1 - S2;
        int k = j / F_OUT, n = j % F_OUT;
        W2rT[(size_t)n * F_HID + k] = f2bf(W2r[j]);
    }
}

// ---------------- layer-1 aggregation: f32 gather -> bf16 mean. block=128 ----------------
__global__ void k_agg1(const float* __restrict__ x, const int* __restrict__ perm,
                       const int* __restrict__ off, ushort* __restrict__ mean) {
    int d = blockIdx.x;
    int beg = off[d], end = off[d + 1];
    int t = threadIdx.x;
    const float4* xp = (const float4*)x;
    float ax = 0.f, ay = 0.f, az = 0.f, aw = 0.f;
    int e = beg;
    for (; e + 3 < end; e += 4) {
        int s0 = perm[e], s1 = perm[e + 1], s2 = perm[e + 2], s3 = perm[e + 3];
        float4 v0 = xp[(size_t)s0 * (F_IN / 4) + t];
        float4 v1 = xp[(size_t)s1 * (F_IN / 4) + t];
        float4 v2 = xp[(size_t)s2 * (F_IN / 4) + t];
        float4 v3 = xp[(size_t)s3 * (F_IN / 4) + t];
        ax += (v0.x + v1.x) + (v2.x + v3.x);
        ay += (v0.y + v1.y) + (v2.y + v3.y);
        az += (v0.z + v1.z) + (v2.z + v3.z);
        aw += (v0.w + v1.w) + (v2.w + v3.w);
    }
    for (; e < end; e++) {
        float4 v0 = xp[(size_t)perm[e] * (F_IN / 4) + t];
        ax += v0.x; ay += v0.y; az += v0.z; aw += v0.w;
    }
    int deg = end - beg;
    float inv = 1.0f / (float)(deg > 0 ? deg : 1);
    ushort4 o;
    o.x = f2bf(ax * inv); o.y = f2bf(ay * inv);
    o.z = f2bf(az * inv); o.w = f2bf(aw * inv);
    ((ushort4*)mean)[(size_t)d * (F_IN / 4) + t] = o;
}

// ---------------- layer-2 aggregation: bf16 gather -> bf16 mean. block=64 ----------------
__global__ void k_agg2(const ushort* __restrict__ h, const int* __restrict__ perm,
                       const int* __restrict__ off, ushort* __restrict__ mean) {
    int d = blockIdx.x;
    int beg = off[d], end = off[d + 1];
    int t = threadIdx.x;
    const ushort4* hp = (const ushort4*)h;
    float a0 = 0.f, a1 = 0.f, a2 = 0.f, a3 = 0.f;
    int e = beg;
    for (; e + 3 < end; e += 4) {
        ushort4 v = hp[(size_t)perm[e] * (F_HID / 4) + t];
        ushort4 u = hp[(size_t)perm[e + 1] * (F_HID / 4) + t];
        ushort4 w = hp[(size_t)perm[e + 2] * (F_HID / 4) + t];
        ushort4 z = hp[(size_t)perm[e + 3] * (F_HID / 4) + t];
        a0 += (bf2f(v.x) + bf2f(u.x)) + (bf2f(w.x) + bf2f(z.x));
        a1 += (bf2f(v.y) + bf2f(u.y)) + (bf2f(w.y) + bf2f(z.y));
        a2 += (bf2f(v.z) + bf2f(u.z)) + (bf2f(w.z) + bf2f(z.z));
        a3 += (bf2f(v.w) + bf2f(u.w)) + (bf2f(w.w) + bf2f(z.w));
    }
    for (; e < end; e++) {
        ushort4 v = hp[(size_t)perm[e] * (F_HID / 4) + t];
        a0 += bf2f(v.x); a1 += bf2f(v.y); a2 += bf2f(v.z); a3 += bf2f(v.w);
    }
    int deg = end - beg;
    float inv = 1.0f / (float)(deg > 0 ? deg : 1);
    ushort4 o;
    o.x = f2bf(a0 * inv); o.y = f2bf(a1 * inv);
    o.z = f2bf(a2 * inv); o.w = f2bf(a3 * inv);
    ((ushort4*)mean)[(size_t)d * (F_HID / 4) + t] = o;
}

// ---------------- dual-A bf16 MFMA GEMM (templated tile / A2 type) ----------------
// C = A1@B1^T + A2@B2^T + bias. A1: MxK bf16. A2: MxK (bf16 or f32, converted on stage).
// B1T,B2T: NxK bf16. 2x2 waves, each wave MF x NF fragments of 16x16. BM=32*MF, BN=32*NF.
#define GBK 32
#define APAD 8
template<int MF, int NF, typename TA2>
__global__ __launch_bounds__(256) void k_gemm(
    const ushort* __restrict__ A1, const TA2* __restrict__ A2,
    const ushort* __restrict__ B1T, const ushort* __restrict__ B2T,
    const float* __restrict__ bias, int M, int N, int K, int relu,
    ushort* __restrict__ Cb, float* __restrict__ Cf)
{
    constexpr int BM = 32 * MF;
    constexpr int BN = 32 * NF;
    __shared__ ushort As[BM][GBK + APAD];
    __shared__ ushort Bs[BN][GBK + APAD];
    int tid = threadIdx.x;
    int lane = tid & 63;
    int wid = tid >> 6;
    int wm = wid >> 1, wn = wid & 1;
    int bm = blockIdx.x * BM, bn = blockIdx.y * BN;

    f32x4 acc[MF][NF];
#pragma unroll
    for (int i = 0; i < MF; i++)
#pragma unroll
        for (int j = 0; j < NF; j++) acc[i][j] = (f32x4){0.f, 0.f, 0.f, 0.f};

    int sr = tid >> 2;
    int sc = (tid & 3) * 8;

    for (int part = 0; part < 2; ++part) {
        const ushort* __restrict__ B = part ? B2T : B1T;
        for (int k0 = 0; k0 < K; k0 += GBK) {
#pragma unroll
            for (int i = 0; i < BM / 64; i++) {
                int r = sr + i * 64;
                bf16x8 av = part
                    ? load8(A2 + (size_t)(bm + r) * K + k0 + sc)
                    : load8(A1 + (size_t)(bm + r) * K + k0 + sc);
                *(bf16x8*)&As[r][sc] = av;
            }
#pragma unroll
            for (int i = 0; i < BN / 64; i++) {
                int r = sr + i * 64;
                *(bf16x8*)&Bs[r][sc] = load8(B + (size_t)(bn + r) * K + k0 + sc);
            }
            __syncthreads();
            bf16x8 af[MF], bfr[NF];
            int r0 = lane & 15;
            int kq = (lane >> 4) * 8;
#pragma unroll
            for (int i = 0; i < MF; i++)
                af[i] = *(const bf16x8*)&As[wm * (MF * 16) + i * 16 + r0][kq];
#pragma unroll
            for (int j = 0; j < NF; j++)
                bfr[j] = *(const bf16x8*)&Bs[wn * (NF * 16) + j * 16 + r0][kq];
#pragma unroll
            for (int i = 0; i < MF; i++)
#pragma unroll
                for (int j = 0; j < NF; j++)
                    acc[i][j] = __builtin_amdgcn_mfma_f32_16x16x32_bf16(af[i], bfr[j], acc[i][j], 0, 0, 0);
            __syncthreads();
        }
    }

    // C/D layout: col = lane&15, row = (lane>>4)*4 + reg
    int cn0 = lane & 15;
    int rq = (lane >> 4) * 4;
#pragma unroll
    for (int i = 0; i < MF; i++) {
#pragma unroll
        for (int j = 0; j < NF; j++) {
            int col = bn + wn * (NF * 16) + j * 16 + cn0;
            float bv = bias[col];
#pragma unroll
            for (int rr = 0; rr < 4; rr++) {
                int row = bm + wm * (MF * 16) + i * 16 + rq + rr;
                float v = acc[i][j][rr] + bv;
                if (relu) v = fmaxf(v, 0.f);
                if (Cb) Cb[(size_t)row * N + col] = f2bf(v);
                if (Cf) Cf[(size_t)row * N + col] = v;
            }
        }
    }
}

static inline size_t align256(size_t x) { return (x + 255) & ~(size_t)255; }

extern "C" void kernel_launch(void* const* d_in, const int* in_sizes, int n_in,
                              void* d_out, int out_size, void* d_ws, size_t ws_size,
                              hipStream_t stream) {
    const float* x = (const float*)d_in[0];
    const int* ei1_src = (const int*)d_in[1];
    const int* ei1_dst = (const int*)d_in[2];
    const int* ei2_src = (const int*)d_in[3];
    const int* ei2_dst = (const int*)d_in[4];
    const float* W1l = (const float*)d_in[5];
    const float* b1 = (const float*)d_in[6];
    const float* W1r = (const float*)d_in[7];
    const float* W2l = (const float*)d_in[8];
    const float* b2 = (const float*)d_in[9];
    const float* W2r = (const float*)d_in[10];
    float* out = (float*)d_out;

    // workspace layout (cnt1+cnt2 contiguous for a single memset)
    char* p = (char*)d_ws;
    size_t o = 0;
    int* cnt1 = (int*)(p + o); o += (size_t)N1 * 4;
    int* cnt2 = (int*)(p + o); o = align256(o + (size_t)N2 * 4);
    int* off1 = (int*)(p + o); o = align256(o + (size_t)(N1 + 1) * 4);
    int* cur1 = (int*)(p + o); o = align256(o + (size_t)N1 * 4);
    int* perm1 = (int*)(p + o); o = align256(o + (size_t)E1c * 4);
    int* off2 = (int*)(p + o); o = align256(o + (size_t)(N2 + 1) * 4);
    int* cur2 = (int*)(p + o); o = align256(o + (size_t)N2 * 4);
    int* perm2 = (int*)(p + o); o = align256(o + (size_t)E2c * 4);
    int* bsum1 = (int*)(p + o); o = align256(o + 64 * 4);
    int* bsum2 = (int*)(p + o); o = align256(o + 64 * 4);
    ushort* mean1 = (ushort*)(p + o); o = align256(o + (size_t)N1 * F_IN * 2);
    ushort* h     = (ushort*)(p + o); o = align256(o + (size_t)N1 * F_HID * 2);
    ushort* mean2 = (ushort*)(p + o); o = align256(o + (size_t)N2 * F_HID * 2);
    ushort* W1lT  = (ushort*)(p + o); o = align256(o + (size_t)F_IN * F_HID * 2);
    ushort* W1rT  = (ushort*)(p + o); o = align256(o + (size_t)F_IN * F_HID * 2);
    ushort* W2lT  = (ushort*)(p + o); o = align256(o + (size_t)F_HID * F_OUT * 2);
    ushort* W2rT  = (ushort*)(p + o); o = align256(o + (size_t)F_HID * F_OUT * 2);

    // zero both histograms with one memset (contiguous)
    hipMemsetAsync(cnt1, 0, (size_t)(N1 + N2) * 4, stream);

    // fused CSR builds
    k_hist2<<<(E1c + E2c + 255) / 256, 256, 0, stream>>>(ei1_dst, cnt1, ei2_dst, cnt2);
    k_scanA<<<N1 / 1024, 1024, 0, stream>>>(cnt1, off1, bsum1, N1);
    k_scanA<<<N2 / 1024, 1024, 0, stream>>>(cnt2, off2, bsum2, N2);
    k_scanB<<<N1 / 1024, 1024, 0, stream>>>(off1, cur1, bsum1, N1, N1 / 1024);
    k_scanB<<<N2 / 1024, 1024, 0, stream>>>(off2, cur2, bsum2, N2, N2 / 1024);
    k_scatter2<<<(E1c + E2c + 255) / 256, 256, 0, stream>>>(
        ei1_src, ei1_dst, cur1, perm1, ei2_src, ei2_dst, cur2, perm2);

    // fused weight transpose+convert
    {
        int total = 2 * F_IN * F_HID + 2 * F_HID * F_OUT;
        k_wt_all<<<(total + 255) / 256, 256, 0, stream>>>(
            W1l, W1r, W2l, W2r, W1lT, W1rT, W2lT, W2rT);
    }

    // layer 1: aggregate + GEMM (A2 = x in f32, converted during staging)
    k_agg1<<<N1, F_IN / 4, 0, stream>>>(x, perm1, off1, mean1);
    {
        dim3 grid(N1 / 128, F_HID / 128);
        k_gemm<4, 4, float><<<grid, 256, 0, stream>>>(mean1, x, W1lT, W1rT, b1,
                                                      N1, F_HID, F_IN, 1, h, nullptr);
    }

    // layer 2: aggregate + GEMM (64x64 tile for more blocks)
    k_agg2<<<N2, F_HID / 4, 0, stream>>>(h, perm2, off2, mean2);
    {
        dim3 grid(N2 / 64, F_OUT / 64);
        k_gemm<2, 2, ushort><<<grid, 256, 0, stream>>>(mean2, h, W2lT, W2rT, b2,
                                                       N2, F_OUT, F_HID, 0, nullptr, out);
    }
}

// Round 5
// 274.087 us; speedup vs baseline: 2.4322x; 1.0195x over previous
//
#include <hip/hip_runtime.h>
#include <hip/hip_bf16.h>

// Problem constants (from reference)
#define N0 409600
#define N1 40960
#define N2 4096
#define E1c 409600
#define E2c 40960
#define F_IN 512
#define F_HID 256
#define F_OUT 128

using bf16x8 = __attribute__((ext_vector_type(8))) short;
using f32x4  = __attribute__((ext_vector_type(4))) float;

__device__ __forceinline__ ushort f2bf(float f) {
    union { float f; unsigned u; } v; v.f = f;
    unsigned r = v.u + 0x7fffu + ((v.u >> 16) & 1u);
    return (ushort)(r >> 16);
}
__device__ __forceinline__ float bf2f(ushort b) {
    union { unsigned u; float f; } v; v.u = ((unsigned)b) << 16;
    return v.f;
}

// load 8 contiguous elements as bf16x8 (identity for bf16, convert for f32)
__device__ __forceinline__ bf16x8 load8(const ushort* p) {
    return *(const bf16x8*)p;
}
__device__ __forceinline__ bf16x8 load8(const float* p) {
    float4 a = *(const float4*)p;
    float4 b = *(const float4*)(p + 4);
    bf16x8 r;
    r[0] = (short)f2bf(a.x); r[1] = (short)f2bf(a.y);
    r[2] = (short)f2bf(a.z); r[3] = (short)f2bf(a.w);
    r[4] = (short)f2bf(b.x); r[5] = (short)f2bf(b.y);
    r[6] = (short)f2bf(b.z); r[7] = (short)f2bf(b.w);
    return r;
}

// ---------------- fused: histogram (both layers) + weight transpose/convert ----------------
__global__ void k_prep(const int* __restrict__ dst1, int* __restrict__ cnt1,
                       const int* __restrict__ dst2, int* __restrict__ cnt2,
                       const float* __restrict__ W1l, const float* __restrict__ W1r,
                       const float* __restrict__ W2l, const float* __restrict__ W2r,
                       ushort* __restrict__ W1lT, ushort* __restrict__ W1rT,
                       ushort* __restrict__ W2lT, ushort* __restrict__ W2rT) {
    int idx = blockIdx.x * blockDim.x + threadIdx.x;
    // histogram part
    if (idx < E1c) atomicAdd(&cnt1[dst1[idx]], 1);
    else if (idx - E1c < E2c) atomicAdd(&cnt2[dst2[idx - E1c]], 1);
    // weight transpose part
    const int S1 = F_IN * F_HID;   // 131072
    const int S2 = F_HID * F_OUT;  // 32768
    if (idx < S1) {
        int k = idx / F_HID, n = idx % F_HID;
        W1lT[(size_t)n * F_IN + k] = f2bf(W1l[idx]);
    } else if (idx < 2 * S1) {
        int j = idx - S1;
        int k = j / F_HID, n = j % F_HID;
        W1rT[(size_t)n * F_IN + k] = f2bf(W1r[j]);
    } else if (idx < 2 * S1 + S2) {
        int j = idx - 2 * S1;
        int k = j / F_OUT, n = j % F_OUT;
        W2lT[(size_t)n * F_HID + k] = f2bf(W2l[j]);
    } else if (idx < 2 * S1 + 2 * S2) {
        int j = idx - 2 * S1 - S2;
        int k = j / F_OUT, n = j % F_OUT;
        W2rT[(size_t)n * F_HID + k] = f2bf(W2r[j]);
    }
}

#define NBLK1 (N1 / 1024)   // 40
#define NBLK2 (N2 / 1024)   // 4

// ---------------- scan phase A (both layers in one grid): per-1024-block scan ----------------
__global__ __launch_bounds__(1024) void k_scanA2(const int* __restrict__ cnt1, int* __restrict__ off1,
                                                 int* __restrict__ bsum1,
                                                 const int* __restrict__ cnt2, int* __restrict__ off2,
                                                 int* __restrict__ bsum2) {
    __shared__ int wsum[16];
    int blk = blockIdx.x;
    const int* cnt; int* off; int* bsum; int lb;
    if (blk < NBLK1) { cnt = cnt1; off = off1; bsum = bsum1; lb = blk; }
    else             { cnt = cnt2; off = off2; bsum = bsum2; lb = blk - NBLK1; }
    int t = threadIdx.x, lane = t & 63, w = t >> 6;
    int i = lb * 1024 + t;
    int v = cnt[i];
    int s = v;
#pragma unroll
    for (int d = 1; d < 64; d <<= 1) {
        int u = __shfl_up(s, d, 64);
        if (lane >= d) s += u;
    }
    if (lane == 63) wsum[w] = s;
    __syncthreads();
    int wpre = 0, total = 0;
#pragma unroll
    for (int j = 0; j < 16; j++) {
        int u = wsum[j];
        if (j < w) wpre += u;
        total += u;
    }
    off[i] = wpre + (s - v);
    if (t == 0) bsum[lb] = total;
}

// ---------------- scan phase B: add block prefix (wave-parallel), write cursor ----------------
__global__ __launch_bounds__(1024) void k_scanB2(int* __restrict__ off1, int* __restrict__ cur1,
                                                 const int* __restrict__ bsum1,
                                                 int* __restrict__ off2, int* __restrict__ cur2,
                                                 const int* __restrict__ bsum2) {
    __shared__ int s_pre, s_tot;
    int blk = blockIdx.x;
    int* off; int* cur; const int* bsum; int lb, nblk, n;
    if (blk < NBLK1) { off = off1; cur = cur1; bsum = bsum1; lb = blk;         nblk = NBLK1; n = N1; }
    else             { off = off2; cur = cur2; bsum = bsum2; lb = blk - NBLK1; nblk = NBLK2; n = N2; }
    int t = threadIdx.x;
    if (t < 64) {
        int v = (t < nblk) ? bsum[t] : 0;
        int p = (t < lb) ? v : 0;
        int tt = v;
#pragma unroll
        for (int d = 32; d >= 1; d >>= 1) {
            p  += __shfl_xor(p, d, 64);
            tt += __shfl_xor(tt, d, 64);
        }
        if (t == 0) { s_pre = p; s_tot = tt; }
    }
    __syncthreads();
    int i = lb * 1024 + t;
    int val = off[i] + s_pre;
    off[i] = val;
    cur[i] = val;
    if (lb == 0 && t == 0) off[n] = s_tot;
}

// ---------------- fused scatter (both layers) ----------------
__global__ void k_scatter2(const int* __restrict__ src1, const int* __restrict__ dst1,
                           int* __restrict__ cur1, int* __restrict__ perm1,
                           const int* __restrict__ src2, const int* __restrict__ dst2,
                           int* __restrict__ cur2, int* __restrict__ perm2) {
    int e = blockIdx.x * blockDim.x + threadIdx.x;
    if (e < E1c) {
        int d = dst1[e];
        int pos = atomicAdd(&cur1[d], 1);
        perm1[pos] = src1[e];
    } else {
        int e2 = e - E1c;
        if (e2 < E2c) {
            int d = dst2[e2];
            int pos = atomicAdd(&cur2[d], 1);
            perm2[pos] = src2[e2];
        }
    }
}

// ---------------- layer-1 aggregation: f32 gather -> bf16 mean. block=128 ----------------
__global__ void k_agg1(const float* __restrict__ x, const int* __restrict__ perm,
                       const int* __restrict__ off, ushort* __restrict__ mean) {
    int d = blockIdx.x;
    int beg = off[d], end = off[d + 1];
    int t = threadIdx.x;
    const float4* xp = (const float4*)x;
    float ax = 0.f, ay = 0.f, az = 0.f, aw = 0.f;
    int e = beg;
    for (; e + 3 < end; e += 4) {
        int s0 = perm[e], s1 = perm[e + 1], s2 = perm[e + 2], s3 = perm[e + 3];
        float4 v0 = xp[(size_t)s0 * (F_IN / 4) + t];
        float4 v1 = xp[(size_t)s1 * (F_IN / 4) + t];
        float4 v2 = xp[(size_t)s2 * (F_IN / 4) + t];
        float4 v3 = xp[(size_t)s3 * (F_IN / 4) + t];
        ax += (v0.x + v1.x) + (v2.x + v3.x);
        ay += (v0.y + v1.y) + (v2.y + v3.y);
        az += (v0.z + v1.z) + (v2.z + v3.z);
        aw += (v0.w + v1.w) + (v2.w + v3.w);
    }
    for (; e < end; e++) {
        float4 v0 = xp[(size_t)perm[e] * (F_IN / 4) + t];
        ax += v0.x; ay += v0.y; az += v0.z; aw += v0.w;
    }
    int deg = end - beg;
    float inv = 1.0f / (float)(deg > 0 ? deg : 1);
    ushort4 o;
    o.x = f2bf(ax * inv); o.y = f2bf(ay * inv);
    o.z = f2bf(az * inv); o.w = f2bf(aw * inv);
    ((ushort4*)mean)[(size_t)d * (F_IN / 4) + t] = o;
}

// ---------------- layer-2 aggregation: bf16 gather -> bf16 mean. block=64 ----------------
__global__ void k_agg2(const ushort* __restrict__ h, const int* __restrict__ perm,
                       const int* __restrict__ off, ushort* __restrict__ mean) {
    int d = blockIdx.x;
    int beg = off[d], end = off[d + 1];
    int t = threadIdx.x;
    const ushort4* hp = (const ushort4*)h;
    float a0 = 0.f, a1 = 0.f, a2 = 0.f, a3 = 0.f;
    int e = beg;
    for (; e + 3 < end; e += 4) {
        ushort4 v = hp[(size_t)perm[e] * (F_HID / 4) + t];
        ushort4 u = hp[(size_t)perm[e + 1] * (F_HID / 4) + t];
        ushort4 w = hp[(size_t)perm[e + 2] * (F_HID / 4) + t];
        ushort4 z = hp[(size_t)perm[e + 3] * (F_HID / 4) + t];
        a0 += (bf2f(v.x) + bf2f(u.x)) + (bf2f(w.x) + bf2f(z.x));
        a1 += (bf2f(v.y) + bf2f(u.y)) + (bf2f(w.y) + bf2f(z.y));
        a2 += (bf2f(v.z) + bf2f(u.z)) + (bf2f(w.z) + bf2f(z.z));
        a3 += (bf2f(v.w) + bf2f(u.w)) + (bf2f(w.w) + bf2f(z.w));
    }
    for (; e < end; e++) {
        ushort4 v = hp[(size_t)perm[e] * (F_HID / 4) + t];
        a0 += bf2f(v.x); a1 += bf2f(v.y); a2 += bf2f(v.z); a3 += bf2f(v.w);
    }
    int deg = end - beg;
    float inv = 1.0f / (float)(deg > 0 ? deg : 1);
    ushort4 o;
    o.x = f2bf(a0 * inv); o.y = f2bf(a1 * inv);
    o.z = f2bf(a2 * inv); o.w = f2bf(a3 * inv);
    ((ushort4*)mean)[(size_t)d * (F_HID / 4) + t] = o;
}

// ---------------- dual-A bf16 MFMA GEMM ----------------
// C = A1@B1^T + A2@B2^T + bias. A1: MxK bf16. A2: MxK (bf16 or f32, converted on stage).
// B1T,B2T: NxK bf16. Waves WM x WN, each wave MF x NF fragments of 16x16.
// BM = WM*MF*16 (must be 64 or 128), BN = WN*NF*16 (must be multiple of 64).
#define GBK 32
#define APAD 8
template<int WM, int WN, int MF, int NF, typename TA2>
__global__ __launch_bounds__(256) void k_gemm(
    const ushort* __restrict__ A1, const TA2* __restrict__ A2,
    const ushort* __restrict__ B1T, const ushort* __restrict__ B2T,
    const float* __restrict__ bias, int M, int N, int K, int relu,
    ushort* __restrict__ Cb, float* __restrict__ Cf)
{
    constexpr int BM = WM * MF * 16;
    constexpr int BN = WN * NF * 16;
    static_assert(BM % 64 == 0 && BN % 64 == 0, "tile must be multiple of 64");
    __shared__ ushort As[BM][GBK + APAD];
    __shared__ ushort Bs[BN][GBK + APAD];
    int tid = threadIdx.x;
    int lane = tid & 63;
    int wid = tid >> 6;
    int wm = wid / WN, wn = wid % WN;
    int bm = blockIdx.x * BM, bn = blockIdx.y * BN;

    f32x4 acc[MF][NF];
#pragma unroll
    for (int i = 0; i < MF; i++)
#pragma unroll
        for (int j = 0; j < NF; j++) acc[i][j] = (f32x4){0.f, 0.f, 0.f, 0.f};

    int sr = tid >> 2;
    int sc = (tid & 3) * 8;

    for (int part = 0; part < 2; ++part) {
        const ushort* __restrict__ B = part ? B2T : B1T;
        for (int k0 = 0; k0 < K; k0 += GBK) {
#pragma unroll
            for (int i = 0; i < BM / 64; i++) {
                int r = sr + i * 64;
                bf16x8 av = part
                    ? load8(A2 + (size_t)(bm + r) * K + k0 + sc)
                    : load8(A1 + (size_t)(bm + r) * K + k0 + sc);
                *(bf16x8*)&As[r][sc] = av;
            }
#pragma unroll
            for (int i = 0; i < BN / 64; i++) {
                int r = sr + i * 64;
                *(bf16x8*)&Bs[r][sc] = load8(B + (size_t)(bn + r) * K + k0 + sc);
            }
            __syncthreads();
            bf16x8 af[MF], bfr[NF];
            int r0 = lane & 15;
            int kq = (lane >> 4) * 8;
#pragma unroll
            for (int i = 0; i < MF; i++)
                af[i] = *(const bf16x8*)&As[wm * (MF * 16) + i * 16 + r0][kq];
#pragma unroll
            for (int j = 0; j < NF; j++)
                bfr[j] = *(const bf16x8*)&Bs[wn * (NF * 16) + j * 16 + r0][kq];
#pragma unroll
            for (int i = 0; i < MF; i++)
#pragma unroll
                for (int j = 0; j < NF; j++)
                    acc[i][j] = __builtin_amdgcn_mfma_f32_16x16x32_bf16(af[i], bfr[j], acc[i][j], 0, 0, 0);
            __syncthreads();
        }
    }

    // C/D layout: col = lane&15, row = (lane>>4)*4 + reg
    int cn0 = lane & 15;
    int rq = (lane >> 4) * 4;
#pragma unroll
    for (int i = 0; i < MF; i++) {
#pragma unroll
        for (int j = 0; j < NF; j++) {
            int col = bn + wn * (NF * 16) + j * 16 + cn0;
            float bv = bias[col];
#pragma unroll
            for (int rr = 0; rr < 4; rr++) {
                int row = bm + wm * (MF * 16) + i * 16 + rq + rr;
                float v = acc[i][j][rr] + bv;
                if (relu) v = fmaxf(v, 0.f);
                if (Cb) Cb[(size_t)row * N + col] = f2bf(v);
                if (Cf) Cf[(size_t)row * N + col] = v;
            }
        }
    }
}

static inline size_t align256(size_t x) { return (x + 255) & ~(size_t)255; }

extern "C" void kernel_launch(void* const* d_in, const int* in_sizes, int n_in,
                              void* d_out, int out_size, void* d_ws, size_t ws_size,
                              hipStream_t stream) {
    const float* x = (const float*)d_in[0];
    const int* ei1_src = (const int*)d_in[1];
    const int* ei1_dst = (const int*)d_in[2];
    const int* ei2_src = (const int*)d_in[3];
    const int* ei2_dst = (const int*)d_in[4];
    const float* W1l = (const float*)d_in[5];
    const float* b1 = (const float*)d_in[6];
    const float* W1r = (const float*)d_in[7];
    const float* W2l = (const float*)d_in[8];
    const float* b2 = (const float*)d_in[9];
    const float* W2r = (const float*)d_in[10];
    float* out = (float*)d_out;

    // workspace layout (cnt1+cnt2 contiguous for a single memset)
    char* p = (char*)d_ws;
    size_t o = 0;
    int* cnt1 = (int*)(p + o); o += (size_t)N1 * 4;
    int* cnt2 = (int*)(p + o); o = align256(o + (size_t)N2 * 4);
    int* off1 = (int*)(p + o); o = align256(o + (size_t)(N1 + 1) * 4);
    int* cur1 = (int*)(p + o); o = align256(o + (size_t)N1 * 4);
    int* perm1 = (int*)(p + o); o = align256(o + (size_t)E1c * 4);
    int* off2 = (int*)(p + o); o = align256(o + (size_t)(N2 + 1) * 4);
    int* cur2 = (int*)(p + o); o = align256(o + (size_t)N2 * 4);
    int* perm2 = (int*)(p + o); o = align256(o + (size_t)E2c * 4);
    int* bsum1 = (int*)(p + o); o = align256(o + 64 * 4);
    int* bsum2 = (int*)(p + o); o = align256(o + 64 * 4);
    ushort* mean1 = (ushort*)(p + o); o = align256(o + (size_t)N1 * F_IN * 2);
    ushort* h     = (ushort*)(p + o); o = align256(o + (size_t)N1 * F_HID * 2);
    ushort* mean2 = (ushort*)(p + o); o = align256(o + (size_t)N2 * F_HID * 2);
    ushort* W1lT  = (ushort*)(p + o); o = align256(o + (size_t)F_IN * F_HID * 2);
    ushort* W1rT  = (ushort*)(p + o); o = align256(o + (size_t)F_IN * F_HID * 2);
    ushort* W2lT  = (ushort*)(p + o); o = align256(o + (size_t)F_HID * F_OUT * 2);
    ushort* W2rT  = (ushort*)(p + o); o = align256(o + (size_t)F_HID * F_OUT * 2);

    // zero both histograms with one memset (contiguous)
    hipMemsetAsync(cnt1, 0, (size_t)(N1 + N2) * 4, stream);

    // fused hist + weight transpose
    {
        int total = E1c + E2c;  // 450560 >= 2*S1+2*S2 = 327680
        k_prep<<<(total + 255) / 256, 256, 0, stream>>>(
            ei1_dst, cnt1, ei2_dst, cnt2,
            W1l, W1r, W2l, W2r, W1lT, W1rT, W2lT, W2rT);
    }
    // fused scans (both layers)
    k_scanA2<<<NBLK1 + NBLK2, 1024, 0, stream>>>(cnt1, off1, bsum1, cnt2, off2, bsum2);
    k_scanB2<<<NBLK1 + NBLK2, 1024, 0, stream>>>(off1, cur1, bsum1, off2, cur2, bsum2);
    // fused scatter
    k_scatter2<<<(E1c + E2c + 255) / 256, 256, 0, stream>>>(
        ei1_src, ei1_dst, cur1, perm1, ei2_src, ei2_dst, cur2, perm2);

    // layer 1: aggregate + GEMM (64x256 tile: A panels read exactly once)
    k_agg1<<<N1, F_IN / 4, 0, stream>>>(x, perm1, off1, mean1);
    {
        dim3 grid(N1 / 64, F_HID / 256);   // (640, 1)
        k_gemm<1, 4, 4, 4, float><<<grid, 256, 0, stream>>>(mean1, x, W1lT, W1rT, b1,
                                                            N1, F_HID, F_IN, 1, h, nullptr);
    }

    // layer 2: aggregate + GEMM (64x64 tile, 128 blocks)
    k_agg2<<<N2, F_HID / 4, 0, stream>>>(h, perm2, off2, mean2);
    {
        dim3 grid(N2 / 64, F_OUT / 64);    // (64, 2)
        k_gemm<2, 2, 2, 2, ushort><<<grid, 256, 0, stream>>>(mean2, h, W2lT, W2rT, b2,
                                                             N2, F_OUT, F_HID, 0, nullptr, out);
    }
}